// Round 7
// baseline (2327.821 us; speedup 1.0000x reference)
//
#include <hip/hip_runtime.h>
#include <hip/hip_bf16.h>
#include <cstdint>

// ---------------------------------------------------------------------------
// Model_2886218023415: GAT/GraphConv graph stage -> BiLSTM+attn x2 -> FC
// Round 10: graph critical-path split — GAT and GraphConv on SEPARATE waves.
//   Rounds 8/9 post-mortem: graph is latency-chain-bound (~17 dependent LDS
//   stages/sample, ~1% of VALU floor); staging fixes under-delivered twice.
//   - 512 thr/block (8 waves), 4 samples: wave 2k = GAT chain for sample k,
//     wave 2k+1 = GraphConv chain for sample k. Both depend only on nf.
//   - 2 block barriers total (post-nf, pre-output). Per-stage code verbatim
//     from round 9 -> bit-identical numerics (absmax must not move).
//   - 24 waves/CU (8 x 3 blocks) vs 12: doubles latency-hiding wave supply.
//   seq/fc/prep frozen = per-dispatch A/B control.
// ---------------------------------------------------------------------------

#define NCH 7
#define SEQ 10
#define NN  10

// Fixed graph (20 directed edges), see reference _edges()
__constant__ int c_src[20] = {0,7,1,7,2,7,3,7,4,8,5,8,6,8,7,8,7,9,8,9};
__constant__ int c_dst[20] = {7,0,7,1,7,2,7,3,8,4,8,5,8,6,8,7,9,7,9,8};
__constant__ int c_in_start[11] = {0,2,4,6,8,10,12,14,21,27,30};
__constant__ int c_in_edge[30] = {1,20, 3,21, 5,22, 7,23, 9,24, 11,25, 13,26,
                                  0,2,4,6,15,17,27,
                                  8,10,12,14,19,28,
                                  16,18,29};
__constant__ int c_gin_start[11] = {0,1,2,3,4,5,6,7,13,18,20};
__constant__ int c_gin_src[20] = {7,7,7,7,8,8,8, 0,1,2,3,8,9, 4,5,6,7,9, 7,8};

__device__ __forceinline__ float fsig(float x){ return 1.f/(1.f + __expf(-x)); }
__device__ __forceinline__ float ftanh(float x){ return 1.f - 2.f/(__expf(2.f*x) + 1.f); }

typedef _Float16 h2v __attribute__((ext_vector_type(2)));
typedef _Float16 f16x4 __attribute__((ext_vector_type(4)));
typedef float    f32x4 __attribute__((ext_vector_type(4)));

#if defined(__has_builtin)
#if __has_builtin(__builtin_amdgcn_fdot2)
#define HAS_FDOT2 1
#endif
#endif

__device__ __forceinline__ float d2(uint32_t a, uint32_t b, float c){
#ifdef HAS_FDOT2
    return __builtin_amdgcn_fdot2(__builtin_bit_cast(h2v, a),
                                  __builtin_bit_cast(h2v, b), c, false);
#else
    union { uint32_t u; _Float16 h[2]; } ua, ub;
    ua.u = a; ub.u = b;
    return c + (float)ua.h[0]*(float)ub.h[0] + (float)ua.h[1]*(float)ub.h[1];
#endif
}

__device__ __forceinline__ f32x4 mfma16(f16x4 a, f16x4 b, f32x4 c){
    return __builtin_amdgcn_mfma_f32_16x16x16f16(a, b, c, 0, 0, 0);
}
__device__ __forceinline__ f16x4 ld4h(const _Float16* p){
    return __builtin_bit_cast(f16x4, *(const uint2*)(p));
}
__device__ __forceinline__ f16x4 ld4hg(const uint32_t* p){
    return __builtin_bit_cast(f16x4, *(const uint2*)(p));
}
__device__ __forceinline__ uint32_t pk2(float a, float b){
    union { _Float16 h[2]; uint32_t u; } x;
    x.h[0] = (_Float16)a; x.h[1] = (_Float16)b; return x.u;
}
__device__ __forceinline__ float2 upk2(uint32_t u){
    union { uint32_t u; _Float16 h[2]; } x; x.u = u;
    return make_float2((float)x.h[0], (float)x.h[1]);
}
#define SBAR() __builtin_amdgcn_sched_barrier(0)

// ---------------- packed-weight layout in d_ws (u32 units) -----------------
// B-fragment tables for mfma_f32_16x16x16_f16:
//   entry (dir, tau, kt): 64 lanes x 2 u32; value at lane l elem e (0..3):
//   W[16*tau + (l&15)][kt*16 + 4*(l>>4) + e]  (zero-padded past K)
#define IH1O 0        // 2 dir x 16 tau x 2 kt  x 128  (K=21 -> pad 32)
#define HH1O 8192     // 2 x 16 x 4 x 128               (K=64)
#define IH2O 24576    // 2 x 16 x 8 x 128               (K=128)
#define HH2O 57344    // 2 x 16 x 4 x 128               (K=64)
#define WA1O 73728    // [128 rows][64 u32]  f16-pair rows (attn, as before)
#define WA2O 81920
#define WPK_TOTAL 90112

__global__ __launch_bounds__(256) void prep_kernel(
    const float* __restrict__ w1f, const float* __restrict__ w1b,
    const float* __restrict__ h1f, const float* __restrict__ h1b,
    const float* __restrict__ w2f, const float* __restrict__ w2b,
    const float* __restrict__ h2f, const float* __restrict__ h2b,
    const float* __restrict__ wa1, const float* __restrict__ wa2,
    uint32_t* __restrict__ wpk)
{
    int i = blockIdx.x * 256 + threadIdx.x;
    if (i >= WPK_TOTAL) return;
    float v0, v1;
    if (i < 73728) {
        const float *sa, *sb; int K, NKT, base;
        if (i < 8192)       { base = 0;     NKT = 2; K = 21;  sa = w1f; sb = w1b; }
        else if (i < 24576) { base = 8192;  NKT = 4; K = 64;  sa = h1f; sb = h1b; }
        else if (i < 57344) { base = 24576; NKT = 8; K = 128; sa = w2f; sb = w2b; }
        else                { base = 57344; NKT = 4; K = 64;  sa = h2f; sb = h2b; }
        int local = i - base;
        int dsz = 16 * NKT * 128;
        const float* src = sa;
        if (local >= dsz) { src = sb; local -= dsz; }
        int entry = local >> 7;            // (tau*NKT + kt)
        int lane  = (local & 127) >> 1;
        int j     = local & 1;
        int tau = entry / NKT, kt = entry - tau * NKT;
        int row = 16 * tau + (lane & 15);
        int kb  = kt * 16 + 4 * (lane >> 4) + 2 * j;
        v0 = (kb     < K) ? src[row * K + kb]     : 0.f;
        v1 = (kb + 1 < K) ? src[row * K + kb + 1] : 0.f;
    } else {
        int local = i - 73728;
        const float* src = wa1;
        if (local >= 8192) { src = wa2; local -= 8192; }
        int row = local >> 6, p = local & 63;
        int d0 = 2 * p;
        v0 = src[row * 128 + d0];
        v1 = src[row * 128 + d0 + 1];
    }
    union { _Float16 h[2]; uint32_t u; } x;
    x.h[0] = (_Float16)v0; x.h[1] = (_Float16)v1;
    wpk[i] = x.u;
}

// ---------------------------------------------------------------------------
// Kernel 1: graph stage — 8 waves/block, 4 samples; wave-pair per sample:
// role 0 = GAT chain, role 1 = GraphConv chain + output. Barrier-free within
// each wave (SBAR discipline); 2 block barriers total.
// ---------------------------------------------------------------------------
struct GWk {
    float    nf[10][10];
    uint32_t xhp[10][64];   // xh as f16 pairs (cols 2j,2j+1)
    uint32_t hp[10][64];    // h  as f16 pairs
    float    as_[10][4], ad_[10][4];
    float    al[30][4];
    float    xh2[10][10];
    float    as2[10], ad2[10], al2[30];
    float    mp[10][10];
    float    agg[10][10];
    float    g[10][33];
    float    gagg[10][33];
    float    bf[10][10];
};

__global__ __launch_bounds__(512) void graph_kernel(
    const float* __restrict__ M,
    const float* __restrict__ W1, const float* __restrict__ as1,
    const float* __restrict__ ad1, const float* __restrict__ b1,
    const float* __restrict__ W2, const float* __restrict__ as2,
    const float* __restrict__ ad2, const float* __restrict__ b2,
    const float* __restrict__ gWrel1, const float* __restrict__ gWroot1,
    const float* __restrict__ gb1,
    const float* __restrict__ gWrel2, const float* __restrict__ gWroot2,
    const float* __restrict__ gb2,
    float* __restrict__ xseq)
{
    __shared__ __align__(16) GWk gw[4];
    __shared__ __align__(16) uint32_t sw2p[640];        // [c][j] = c*64+j
    __shared__ uint32_t sa1p[64], sd1p[64];
    __shared__ float swrel1[320], swroot1[320];         // [f*32+c]
    __shared__ float swrel2[320], swroot2[320];         // [f*10+c]
    __shared__ __align__(16) float sb1[128];
    __shared__ float sb2[12], sgb1[32], sgb2[12];
    __shared__ int sin_start[12], sin_edge[32];
    __shared__ int sgin_start[12], sgin_src[20], ssrc[20], sdst[20];

    const int tid = threadIdx.x;
    const int wid = tid >> 6;          // 0..7
    const int k   = wid >> 1;          // sample slot 0..3
    const int role= wid & 1;           // 0 = GAT, 1 = GraphConv + IO
    const int l   = tid & 63;
    const int b   = blockIdx.x * 4 + k;

    // ---- shared staging (all 512 threads) ----
    for (int i = tid; i < 640; i += 512) {
        int c = i >> 6, j = i & 63;
        sw2p[i] = pk2(W2[(2 * j) * 10 + c], W2[(2 * j + 1) * 10 + c]);
    }
    if (tid < 64)       sa1p[tid]      = pk2(as1[2 * tid], as1[2 * tid + 1]);
    else if (tid < 128) sd1p[tid - 64] = pk2(ad1[2 * (tid - 64)], ad1[2 * (tid - 64) + 1]);
    for (int i = tid; i < 320; i += 512) {
        swrel1[i] = gWrel1[i]; swroot1[i] = gWroot1[i];
        swrel2[i] = gWrel2[i]; swroot2[i] = gWroot2[i];
    }
    if (tid < 128) sb1[tid] = b1[tid];
    if (tid >= 128 && tid < 138) sb2[tid - 128] = b2[tid - 128];
    if (tid >= 144 && tid < 176) sgb1[tid - 144] = gb1[tid - 144];
    if (tid >= 176 && tid < 186) sgb2[tid - 176] = gb2[tid - 176];
    if (tid >= 192 && tid < 203) {
        sin_start[tid - 192]  = c_in_start[tid - 192];
        sgin_start[tid - 192] = c_gin_start[tid - 192];
    }
    if (tid >= 203 && tid < 233) sin_edge[tid - 203] = c_in_edge[tid - 203];
    if (tid >= 233 && tid < 253) {
        int e = tid - 233;
        sgin_src[e] = c_gin_src[e]; ssrc[e] = c_src[e]; sdst[e] = c_dst[e];
    }

    // ---- nf staging (GAT wave of each pair) ----
    GWk& Wv = gw[k];
    float2 w1r[10];
    if (role == 0) {
        const float* Mb = M + (size_t)b * 70;
        for (int i = l; i < 100; i += 64) {
            int n = i / 10, f = i - n * 10;
            Wv.nf[n][f] = (n < 7) ? Mb[n * 10 + f] : 0.f;
        }
        #pragma unroll
        for (int f = 0; f < 10; f++)
            w1r[f] = *(const float2*)(W1 + f * 128 + 2 * l);
    }
    __syncthreads();

    if (role == 0) {
        // =================== GAT chain (verbatim round-9 math) ===================
        // stage 1: xh = nf @ W1 (lane owns col pair 2l, 2l+1)
        #pragma unroll
        for (int n = 0; n < 10; n++) {
            float a0 = 0.f, a1 = 0.f;
            #pragma unroll
            for (int f = 0; f < 10; f++) {
                float x = Wv.nf[n][f];
                a0 += x * w1r[f].x; a1 += x * w1r[f].y;
            }
            Wv.xhp[n][l] = pk2(a0, a1);
        }
        SBAR();

        // stage 2: a_s/a_d per (node, head)
        if (l < 40) {
            int n = l >> 2, h = l & 3;
            float va = 0.f, vd = 0.f;
            #pragma unroll
            for (int cp = 0; cp < 16; cp++) {
                uint32_t x = Wv.xhp[n][h * 16 + cp];
                va = d2(x, sa1p[h * 16 + cp], va);
                vd = d2(x, sd1p[h * 16 + cp], vd);
            }
            Wv.as_[n][h] = va; Wv.ad_[n][h] = vd;
        }
        SBAR();

        // stage 3: edge scores + leaky relu
        for (int i = l; i < 120; i += 64) {
            int e = i >> 2, h = i & 3;
            int sn = (e < 20) ? ssrc[e] : e - 20;
            int dn = (e < 20) ? sdst[e] : e - 20;
            float v = Wv.as_[sn][h] + Wv.ad_[dn][h];
            Wv.al[e][h] = (v >= 0.f) ? v : 0.2f * v;
        }
        SBAR();

        // stage 4: edge softmax by dst
        if (l < 40) {
            int n = l >> 2, h = l & 3;
            int st = sin_start[n], en = sin_start[n + 1];
            float m = -1e30f;
            for (int j = st; j < en; j++) m = fmaxf(m, Wv.al[sin_edge[j]][h]);
            float den = 0.f;
            for (int j = st; j < en; j++) den += __expf(Wv.al[sin_edge[j]][h] - m);
            float inv = 1.f / den;
            for (int j = st; j < en; j++) {
                int e = sin_edge[j];
                Wv.al[e][h] = __expf(Wv.al[e][h] - m) * inv;
            }
        }
        SBAR();

        // stage 5: h = relu(bias + sum alpha*xh), col-pair per iter
        for (int i = l; i < 640; i += 64) {
            int n = i >> 6, p = i & 63;
            int h = p >> 4;
            int st = sin_start[n], en = sin_start[n + 1];
            float o0 = sb1[2 * p], o1 = sb1[2 * p + 1];
            for (int j = st; j < en; j++) {
                int e = sin_edge[j];
                int sn = (e < 20) ? ssrc[e] : e - 20;
                float al = Wv.al[e][h];
                float2 xf = upk2(Wv.xhp[sn][p]);
                o0 += al * xf.x; o1 += al * xf.y;
            }
            Wv.hp[n][p] = pk2(fmaxf(o0, 0.f), fmaxf(o1, 0.f));
        }
        SBAR();

        // stage 6: xh2 = h @ W2 (LDS-only, 2-acc ILP)
        for (int i = l; i < 100; i += 64) {
            int n = i / 10, c = i - (i / 10) * 10;
            float a0 = 0.f, a1 = 0.f;
            #pragma unroll 8
            for (int j = 0; j < 64; j += 2) {
                a0 = d2(Wv.hp[n][j],     sw2p[c * 64 + j],     a0);
                a1 = d2(Wv.hp[n][j + 1], sw2p[c * 64 + j + 1], a1);
            }
            Wv.xh2[n][c] = a0 + a1;
        }
        SBAR();

        // stage 7: GAT-2 attention scalars
        if (l < 20) {
            int n = (l < 10) ? l : l - 10;
            const float* av = (l < 10) ? as2 : ad2;
            float v = 0.f;
            #pragma unroll
            for (int c = 0; c < 10; c++) v += Wv.xh2[n][c] * av[c];
            if (l < 10) Wv.as2[n] = v; else Wv.ad2[n] = v;
        }
        SBAR();
        if (l < 30) {
            int e = l;
            int sn = (e < 20) ? ssrc[e] : e - 20;
            int dn = (e < 20) ? sdst[e] : e - 20;
            float v = Wv.as2[sn] + Wv.ad2[dn];
            Wv.al2[e] = (v >= 0.f) ? v : 0.2f * v;
        }
        SBAR();
        if (l < 10) {
            int st = sin_start[l], en = sin_start[l + 1];
            float m = -1e30f;
            for (int j = st; j < en; j++) m = fmaxf(m, Wv.al2[sin_edge[j]]);
            float den = 0.f;
            for (int j = st; j < en; j++) den += __expf(Wv.al2[sin_edge[j]] - m);
            float inv = 1.f / den;
            for (int j = st; j < en; j++) Wv.al2[sin_edge[j]] = __expf(Wv.al2[sin_edge[j]] - m) * inv;
        }
        SBAR();
        for (int i = l; i < 100; i += 64) {
            int n = i / 10, c = i - (i / 10) * 10;
            int st = sin_start[n], en = sin_start[n + 1];
            float o = sb2[c];
            for (int j = st; j < en; j++) {
                int e = sin_edge[j];
                int sn = (e < 20) ? ssrc[e] : e - 20;
                o += Wv.al2[e] * Wv.xh2[sn][c];
            }
            Wv.mp[n][c] = o;
        }
    } else {
        // =================== GraphConv chain (verbatim round-9 math) =============
        for (int i = l; i < 100; i += 64) {
            int n = i / 10, f = i - (i / 10) * 10;
            int st = sgin_start[n], en = sgin_start[n + 1];
            float a = 0.f;
            for (int j = st; j < en; j++) a += Wv.nf[sgin_src[j]][f];
            Wv.agg[n][f] = a;
        }
        SBAR();
        for (int i = l; i < 320; i += 64) {
            int n = i >> 5, c = i & 31;
            float v = sgb1[c];
            #pragma unroll
            for (int f = 0; f < 10; f++)
                v += Wv.agg[n][f] * swrel1[f * 32 + c] + Wv.nf[n][f] * swroot1[f * 32 + c];
            Wv.g[n][c] = fmaxf(v, 0.f);
        }
        SBAR();
        for (int i = l; i < 320; i += 64) {
            int n = i >> 5, c = i & 31;
            int st = sgin_start[n], en = sgin_start[n + 1];
            float a = 0.f;
            for (int j = st; j < en; j++) a += Wv.g[sgin_src[j]][c];
            Wv.gagg[n][c] = a;
        }
        SBAR();
        for (int i = l; i < 100; i += 64) {
            int n = i / 10, c = i - (i / 10) * 10;
            float v = sgb2[c];
            #pragma unroll
            for (int f = 0; f < 32; f++)
                v += Wv.gagg[n][f] * swrel2[f * 10 + c] + Wv.g[n][f] * swroot2[f * 10 + c];
            Wv.bf[n][c] = v;
        }
    }
    __syncthreads();

    // ---- output staging (GraphConv wave of each pair) ----
    if (role == 1) {
        float* xo = xseq + (size_t)b * 210;
        for (int i = l; i < 210; i += 64) {
            int t = i / 21, kk = i - (i / 21) * 21;
            float v;
            if (kk < 7)       v = Wv.nf[kk][t];
            else if (kk < 14) v = Wv.mp[kk - 7][t];
            else              v = Wv.bf[kk - 14][t];
            xo[i] = v;
        }
    }
}

// ---------------------------------------------------------------------------
// seq LDS regions (per block = 8 samples):
//   sR1 [8][680]u32 : X2 f16 [8][10][36] -> attn Q f16 [s][10][136] -> A2 (same slots)
//   sO2 [8][680]u32 : BiLSTM output f16 [s][10][136] (cols 0..127 used)
//   sSC [8][104]f32 : attn scores
//   sH  [2dir][2buf][8][72]f16 : hidden state (double-buffered)
// ---------------------------------------------------------------------------

// One BiLSTM layer, both directions concurrently. 4 waves:
//   wave w: dir = w>>1 (0 fwd, 1 bwd), unit-groups ub=(w&1)*2 .. +1.
//   gate g, unit-group v -> MFMA N-tile tau = 4g + v.
// C/D: col = l&15 (gate within tile), row = 4*(l>>4)+reg (sample).
// A: row = l&15 (clamped &7), k = kt*16 + 4*(l>>4) + e.
template<int L>
__device__ __forceinline__ void rec_layer(
    const uint32_t* __restrict__ wpk,
    const float* __restrict__ bf, const float* __restrict__ bb,
    uint32_t* __restrict__ sR1, uint32_t* __restrict__ sO2,
    uint32_t* __restrict__ sH, int w, int l)
{
    constexpr int NKT = (L == 1) ? 2 : 8;
    const uint32_t* bih = wpk + ((L == 1) ? IH1O : IH2O);
    const uint32_t* bhh = wpk + ((L == 1) ? HH1O : HH2O);
    const int dir = w >> 1;
    const int ub  = (w & 1) * 2;
    bih += dir * 16 * NKT * 128;
    bhh += dir * 16 * 4 * 128;
    const float* bias = dir ? bb : bf;
    const int ln = l & 15, lg = l >> 4;
    const int arow = l & 7, asub = 4 * lg;
    float bv[2][4];
    #pragma unroll
    for (int up = 0; up < 2; ++up)
        #pragma unroll
        for (int g = 0; g < 4; ++g)
            bv[up][g] = bias[64 * g + 16 * (ub + up) + ln];
    float cs[2][4] = {{0.f,0.f,0.f,0.f},{0.f,0.f,0.f,0.f}};
    const _Float16* Axh = (const _Float16*)sR1;
    _Float16* Hh  = (_Float16*)sH;
    _Float16* O2h = (_Float16*)sO2;
    for (int ss = 0; ss < 10; ++ss) {
        const int t = dir ? 9 - ss : ss;
        const int cur = ss & 1;
        f16x4 ax[NKT];
        #pragma unroll
        for (int kt = 0; kt < NKT; ++kt) {
            const int fo = (L == 1) ? (arow * 360 + t * 36 + kt * 16 + asub)
                                    : (arow * 1360 + t * 136 + kt * 16 + asub);
            ax[kt] = ld4h(Axh + fo);
        }
        f16x4 ah[4];
        #pragma unroll
        for (int kt = 0; kt < 4; ++kt)
            ah[kt] = ld4h(Hh + ((dir * 2 + cur) * 8 + arow) * 72 + kt * 16 + asub);
        #pragma unroll
        for (int up = 0; up < 2; ++up) {
            const int v = ub + up;
            f32x4 G[4];
            #pragma unroll
            for (int g = 0; g < 4; ++g) {
                const int tau = 4 * g + v;
                f32x4 c = { bv[up][g], bv[up][g], bv[up][g], bv[up][g] };
                #pragma unroll
                for (int kt = 0; kt < NKT; ++kt)
                    c = mfma16(ax[kt], ld4hg(bih + (tau * NKT + kt) * 128 + 2 * l), c);
                #pragma unroll
                for (int kt = 0; kt < 4; ++kt)
                    c = mfma16(ah[kt], ld4hg(bhh + (tau * 4 + kt) * 128 + 2 * l), c);
                G[g] = c;
            }
            if (l < 32) {   // rows 0..7 = real samples
                #pragma unroll
                for (int r = 0; r < 4; ++r) {
                    const int s = asub + r;
                    const float ig = fsig(G[0][r]), fg = fsig(G[1][r]);
                    const float gg = ftanh(G[2][r]), og = fsig(G[3][r]);
                    const float c2 = fg * cs[up][r] + ig * gg;
                    cs[up][r] = c2;
                    const float hv = og * ftanh(c2);
                    const int u = 16 * v + ln;
                    Hh[((dir * 2 + (1 - cur)) * 8 + s) * 72 + u] = (_Float16)hv;
                    O2h[s * 1360 + t * 136 + dir * 64 + u] = (_Float16)hv;
                }
            }
        }
        __syncthreads();
    }
}

// Self-attention for ONE sample, one full wave (round-5 known-good structure).
// Q written into (and A2 output overwrites) this sample's region of sR1.
__device__ __forceinline__ void attn_one(
    const uint32_t* __restrict__ wa, const float* __restrict__ ba,
    uint32_t* __restrict__ sR1, const uint32_t* __restrict__ sO2,
    float* __restrict__ sSC, int l, int s, float* __restrict__ outg)
{
    const uint32_t* O2s = sO2 + s * 680;
    uint32_t* Q2s = sR1 + s * 680;
    float* sc = sSC + s * 104;

    float qa0[10], qa1[10];
    {
        float b0 = ba[l], b1 = ba[64 + l];
        #pragma unroll
        for (int t = 0; t < 10; t++) { qa0[t] = b0; qa1[t] = b1; }
    }
    #pragma unroll 4
    for (int c = 0; c < 16; c++) {
        uint4 w0 = *(const uint4*)(wa + l * 64 + c * 4);
        uint4 w1 = *(const uint4*)(wa + (64 + l) * 64 + c * 4);
        #pragma unroll
        for (int t = 0; t < 10; t++) {
            uint4 o = *(const uint4*)(O2s + t * 68 + c * 4);
            qa0[t] = d2(w0.w, o.w, d2(w0.z, o.z, d2(w0.y, o.y, d2(w0.x, o.x, qa0[t]))));
            qa1[t] = d2(w1.w, o.w, d2(w1.z, o.z, d2(w1.y, o.y, d2(w1.x, o.x, qa1[t]))));
        }
    }
    _Float16* q2h = (_Float16*)Q2s;
    #pragma unroll
    for (int t = 0; t < 10; t++) {
        q2h[t * 136 + l]      = (_Float16)ftanh(qa0[t]);
        q2h[t * 136 + 64 + l] = (_Float16)ftanh(qa1[t]);
    }
    #pragma unroll
    for (int r = 0; r < 2; r++) {
        int idx = l + r * 64;
        if (idx < 100) {
            int q = idx / 10, k = idx - 10 * q;
            float sv = 0.f;
            #pragma unroll
            for (int m = 0; m < 16; m++) {
                uint4 a = *(const uint4*)(Q2s + q * 68 + m * 4);
                uint4 b = *(const uint4*)(O2s + k * 68 + m * 4);
                sv = d2(a.w, b.w, d2(a.z, b.z, d2(a.y, b.y, d2(a.x, b.x, sv))));
            }
            sc[idx] = sv;
        }
    }
    if (l < 10) {
        float m = -1e30f;
        #pragma unroll
        for (int k = 0; k < 10; k++) m = fmaxf(m, sc[l * 10 + k]);
        float den = 0.f, e[10];
        #pragma unroll
        for (int k = 0; k < 10; k++) { e[k] = __expf(sc[l * 10 + k] - m); den += e[k]; }
        float inv = 1.f / den;
        #pragma unroll
        for (int k = 0; k < 10; k++) sc[l * 10 + k] = e[k] * inv;
    }
    float of0[10], of1[10];
    {
        const _Float16* o2h = (const _Float16*)O2s;
        #pragma unroll
        for (int k = 0; k < 10; k++) {
            of0[k] = (float)o2h[k * 136 + l];
            of1[k] = (float)o2h[k * 136 + 64 + l];
        }
    }
    float pa0[10], pa1[10];
    #pragma unroll
    for (int t = 0; t < 10; t++) { pa0[t] = 0.f; pa1[t] = 0.f; }
    #pragma unroll
    for (int k = 0; k < 10; k++) {
        float o0 = of0[k], o1 = of1[k];
        #pragma unroll
        for (int t = 0; t < 10; t++) {
            float sv = sc[t * 10 + k];
            pa0[t] += sv * o0; pa1[t] += sv * o1;
        }
    }
    if (outg) {
        float s0 = 0.f, s1 = 0.f;
        #pragma unroll
        for (int t = 0; t < 10; t++) { s0 += pa0[t]; s1 += pa1[t]; }
        outg[l] = s0 * 0.1f; outg[64 + l] = s1 * 0.1f;
    } else {
        _Float16* a2h = (_Float16*)Q2s;   // A2 overwrites Q (Q dead after scores)
        #pragma unroll
        for (int t = 0; t < 10; t++) {
            a2h[t * 136 + l]      = (_Float16)pa0[t];
            a2h[t * 136 + 64 + l] = (_Float16)pa1[t];
        }
    }
}

// ---------------------------------------------------------------------------
// Kernel 2: sequence stage — 8 samples per block, 4 waves, MFMA recurrence.
// ---------------------------------------------------------------------------
__global__ __launch_bounds__(256) void seq_kernel(
    const float* __restrict__ xseq, const uint32_t* __restrict__ wpk,
    const float* __restrict__ b1f, const float* __restrict__ b1b,
    const float* __restrict__ b2f, const float* __restrict__ b2b,
    const float* __restrict__ ba1, const float* __restrict__ ba2,
    float* __restrict__ xbar)
{
    __shared__ __align__(16) uint32_t sR1[8 * 680];
    __shared__ __align__(16) uint32_t sO2[8 * 680];
    __shared__ __align__(16) float    sSC[8 * 104];
    __shared__ __align__(16) uint32_t sH[1152];
    const int tid = threadIdx.x;
    const int w = tid >> 6, l = tid & 63;
    const int b0 = blockIdx.x * 8;

    // stage X: xseq f32 [8][10][21] -> f16 [8][10][36] (zero-padded)
    {
        _Float16* xh = (_Float16*)sR1;
        const float* xs = xseq + (size_t)b0 * 210;
        for (int i = tid; i < 2880; i += 256) {
            int s = i / 360, r = i - s * 360;
            int t = r / 36, k = r - t * 36;
            float v = (k < 21) ? xs[s * 210 + t * 21 + k] : 0.f;
            xh[s * 360 + t * 36 + k] = (_Float16)v;
        }
    }
    for (int i = tid; i < 1152; i += 256) sH[i] = 0;
    __syncthreads();

    rec_layer<1>(wpk, b1f, b1b, sR1, sO2, sH, w, l);

    for (int smp = 0; smp < 2; ++smp)
        attn_one(wpk + WA1O, ba1, sR1, sO2, sSC, l, 2 * w + smp, nullptr);
    __syncthreads();
    for (int i = tid; i < 1152; i += 256) sH[i] = 0;
    __syncthreads();

    rec_layer<2>(wpk, b2f, b2b, sR1, sO2, sH, w, l);

    for (int smp = 0; smp < 2; ++smp) {
        int s = 2 * w + smp;
        attn_one(wpk + WA2O, ba2, sR1, sO2, sSC, l, s,
                 xbar + (size_t)(b0 + s) * 128);
    }
}

// ---------------------------------------------------------------------------
// Kernel 3: FC  out[b][u] = xbar[b] . W[u] + bias[u]
// ---------------------------------------------------------------------------
__global__ __launch_bounds__(256) void fc_kernel(
    const float* __restrict__ xbar, const float* __restrict__ W,
    const float* __restrict__ fb, float* __restrict__ out, int B)
{
    __shared__ __align__(16) float s_xb[64 * 132];
    const int tid = threadIdx.x;
    const int b0 = blockIdx.y * 64;
    const int u0 = blockIdx.x * 64;

    for (int i = tid; i < 64 * 128; i += 256) {
        int s = i >> 7, k = i & 127;
        int bb = b0 + s;
        s_xb[s * 132 + k] = (bb < B) ? xbar[(size_t)bb * 128 + k] : 0.f;
    }
    __syncthreads();

    const int tx = tid & 15, ty = tid >> 4;
    float acc[4][4] = {};
    for (int k = 0; k < 128; k += 4) {
        float4 wv[4], xv[4];
        #pragma unroll
        for (int j = 0; j < 4; j++) {
            int u = u0 + tx + 16 * j;
            int uc = (u < 1000) ? u : 999;
            wv[j] = *(const float4*)(W + (size_t)uc * 128 + k);
        }
        #pragma unroll
        for (int si = 0; si < 4; si++) {
            int s = ty + 16 * si;
            xv[si] = *(const float4*)(s_xb + s * 132 + k);
        }
        #pragma unroll
        for (int j = 0; j < 4; j++)
            #pragma unroll
            for (int si = 0; si < 4; si++)
                acc[j][si] += wv[j].x*xv[si].x + wv[j].y*xv[si].y
                            + wv[j].z*xv[si].z + wv[j].w*xv[si].w;
    }
    #pragma unroll
    for (int j = 0; j < 4; j++) {
        int u = u0 + tx + 16 * j;
        if (u < 1000) {
            float bb = fb[u];
            #pragma unroll
            for (int si = 0; si < 4; si++) {
                int bsm = b0 + ty + 16 * si;
                if (bsm < B) out[(size_t)bsm * 1000 + u] = acc[j][si] + bb;
            }
        }
    }
}

// ---------------------------------------------------------------------------
extern "C" void kernel_launch(void* const* d_in, const int* in_sizes, int n_in,
                              void* d_out, int out_size, void* d_ws, size_t ws_size,
                              hipStream_t stream)
{
    const float* M       = (const float*)d_in[0];
    const float* ga1_W   = (const float*)d_in[1];
    const float* ga1_as  = (const float*)d_in[2];
    const float* ga1_ad  = (const float*)d_in[3];
    const float* ga1_b   = (const float*)d_in[4];
    const float* ga2_W   = (const float*)d_in[5];
    const float* ga2_as  = (const float*)d_in[6];
    const float* ga2_ad  = (const float*)d_in[7];
    const float* ga2_b   = (const float*)d_in[8];
    const float* gp1_Wrel  = (const float*)d_in[9];
    const float* gp1_Wroot = (const float*)d_in[10];
    const float* gp1_b     = (const float*)d_in[11];
    const float* gp2_Wrel  = (const float*)d_in[12];
    const float* gp2_Wroot = (const float*)d_in[13];
    const float* gp2_b     = (const float*)d_in[14];
    const float* l1f_Wih = (const float*)d_in[15];
    const float* l1f_Whh = (const float*)d_in[16];
    const float* l1f_b   = (const float*)d_in[17];
    const float* l1b_Wih = (const float*)d_in[18];
    const float* l1b_Whh = (const float*)d_in[19];
    const float* l1b_b   = (const float*)d_in[20];
    const float* l2f_Wih = (const float*)d_in[21];
    const float* l2f_Whh = (const float*)d_in[22];
    const float* l2f_b   = (const float*)d_in[23];
    const float* l2b_Wih = (const float*)d_in[24];
    const float* l2b_Whh = (const float*)d_in[25];
    const float* l2b_b   = (const float*)d_in[26];
    const float* a1_Wa   = (const float*)d_in[27];
    const float* a1_ba   = (const float*)d_in[28];
    const float* a2_Wa   = (const float*)d_in[29];
    const float* a2_ba   = (const float*)d_in[30];
    const float* fc_W    = (const float*)d_in[31];
    const float* fc_b    = (const float*)d_in[32];

    const int B = in_sizes[0] / 70;    // 32768

    float* xseq = (float*)d_ws;                                       // [B,10,21]
    float* xbar = (float*)((char*)d_ws + (size_t)B * 210 * 4);        // [B,128]
    uint32_t* wpk = (uint32_t*)((char*)d_ws + (size_t)B * 210 * 4
                                            + (size_t)B * 128 * 4);   // packed weights

    prep_kernel<<<(WPK_TOTAL + 255) / 256, 256, 0, stream>>>(
        l1f_Wih, l1b_Wih, l1f_Whh, l1b_Whh,
        l2f_Wih, l2b_Wih, l2f_Whh, l2b_Whh,
        a1_Wa, a2_Wa, wpk);

    graph_kernel<<<B / 4, 512, 0, stream>>>(M,
        ga1_W, ga1_as, ga1_ad, ga1_b,
        ga2_W, ga2_as, ga2_ad, ga2_b,
        gp1_Wrel, gp1_Wroot, gp1_b,
        gp2_Wrel, gp2_Wroot, gp2_b,
        xseq);

    seq_kernel<<<B / 8, 256, 0, stream>>>(xseq, wpk,
        l1f_b, l1b_b, l2f_b, l2b_b, a1_ba, a2_ba, xbar);

    dim3 fgrid((1000 + 63) / 64, (B + 63) / 64);
    fc_kernel<<<fgrid, 256, 0, stream>>>(xbar, fc_W, fc_b, (float*)d_out, B);
}

// Round 8
// 2210.513 us; speedup vs baseline: 1.0531x; 1.0531x over previous
//
#include <hip/hip_runtime.h>
#include <hip/hip_bf16.h>
#include <cstdint>

// ---------------------------------------------------------------------------
// Model_2886218023415: GAT/GraphConv graph stage -> BiLSTM+attn x2 -> FC
// Round 11: seq rec_layer on K=32 MFMA (v_mfma_f32_16x16x32_f16).
//   Round-10 post-mortem: graph resisted 3 latency theories (~780us floor);
//   back to seq (1444us, 62%). Per step/wave the K-loop issued 96 MFMA +
//   96 uint2 global B-loads + ~200 VALU addressing. K=32 shape halves all
//   three: 48 MFMA + 48 uint4 loads. A-frag layout = K=16 layout applied
//   twice (chunk0 k=4m+e, chunk1 k=16+4m+e, m=l>>4); C/D unchanged (16x16).
//   prep repacks B-tables to 4-u32/lane frags (same sizes/offsets).
//   graph/fc/prep frozen = per-dispatch A/B control. absmax may shift ~1ulp
//   (association inside K=32); blowup => layout hypothesis falsified.
// ---------------------------------------------------------------------------

#define NCH 7
#define SEQ 10
#define NN  10

// Fixed graph (20 directed edges), see reference _edges()
__constant__ int c_src[20] = {0,7,1,7,2,7,3,7,4,8,5,8,6,8,7,8,7,9,8,9};
__constant__ int c_dst[20] = {7,0,7,1,7,2,7,3,8,4,8,5,8,6,8,7,9,7,9,8};
__constant__ int c_in_start[11] = {0,2,4,6,8,10,12,14,21,27,30};
__constant__ int c_in_edge[30] = {1,20, 3,21, 5,22, 7,23, 9,24, 11,25, 13,26,
                                  0,2,4,6,15,17,27,
                                  8,10,12,14,19,28,
                                  16,18,29};
__constant__ int c_gin_start[11] = {0,1,2,3,4,5,6,7,13,18,20};
__constant__ int c_gin_src[20] = {7,7,7,7,8,8,8, 0,1,2,3,8,9, 4,5,6,7,9, 7,8};

__device__ __forceinline__ float fsig(float x){ return 1.f/(1.f + __expf(-x)); }
__device__ __forceinline__ float ftanh(float x){ return 1.f - 2.f/(__expf(2.f*x) + 1.f); }

typedef _Float16 h2v __attribute__((ext_vector_type(2)));
typedef _Float16 f16x4 __attribute__((ext_vector_type(4)));
typedef _Float16 f16x8 __attribute__((ext_vector_type(8)));
typedef float    f32x4 __attribute__((ext_vector_type(4)));

#if defined(__has_builtin)
#if __has_builtin(__builtin_amdgcn_fdot2)
#define HAS_FDOT2 1
#endif
#endif

__device__ __forceinline__ float d2(uint32_t a, uint32_t b, float c){
#ifdef HAS_FDOT2
    return __builtin_amdgcn_fdot2(__builtin_bit_cast(h2v, a),
                                  __builtin_bit_cast(h2v, b), c, false);
#else
    union { uint32_t u; _Float16 h[2]; } ua, ub;
    ua.u = a; ub.u = b;
    return c + (float)ua.h[0]*(float)ub.h[0] + (float)ua.h[1]*(float)ub.h[1];
#endif
}

__device__ __forceinline__ f32x4 mfma32(f16x8 a, f16x8 b, f32x4 c){
    return __builtin_amdgcn_mfma_f32_16x16x32_f16(a, b, c, 0, 0, 0);
}
// A-fragment for 16x16x32: two K=16-style 4-elem chunks (k=4m+e, k=16+4m+e).
// p points at chunk0 (f16 units); chunk1 is at p+16.
__device__ __forceinline__ f16x8 ldfragA(const _Float16* p){
    uint2 lo = *(const uint2*)(p);
    uint2 hi = *(const uint2*)(p + 16);
    uint4 u = make_uint4(lo.x, lo.y, hi.x, hi.y);
    return __builtin_bit_cast(f16x8, u);
}
__device__ __forceinline__ f16x8 ldfragB(const uint32_t* p){
    return __builtin_bit_cast(f16x8, *(const uint4*)(p));
}
__device__ __forceinline__ uint32_t pk2(float a, float b){
    union { _Float16 h[2]; uint32_t u; } x;
    x.h[0] = (_Float16)a; x.h[1] = (_Float16)b; return x.u;
}
__device__ __forceinline__ float2 upk2(uint32_t u){
    union { uint32_t u; _Float16 h[2]; } x; x.u = u;
    return make_float2((float)x.h[0], (float)x.h[1]);
}
#define SBAR() __builtin_amdgcn_sched_barrier(0)

// ---------------- packed-weight layout in d_ws (u32 units) -----------------
// B-fragment tables for mfma_f32_16x16x32_f16:
//   entry (dir, tau, kt32): 64 lanes x 4 u32 (8 f16). Lane l, elem e (0..7):
//   W[16*tau + (l&15)][kt32*32 + (e<4 ? 4*(l>>4)+e : 16+4*(l>>4)+e-4)]
//   (zero-padded past K).
#define IH1O 0        // 2 dir x 16 tau x 1 kt32 x 256  (K=21 -> pad 32)
#define HH1O 8192     // 2 x 16 x 2 x 256               (K=64)
#define IH2O 24576    // 2 x 16 x 4 x 256               (K=128)
#define HH2O 57344    // 2 x 16 x 2 x 256               (K=64)
#define WA1O 73728    // [128 rows][64 u32]  f16-pair rows (attn, unchanged)
#define WA2O 81920
#define WPK_TOTAL 90112

__global__ __launch_bounds__(256) void prep_kernel(
    const float* __restrict__ w1f, const float* __restrict__ w1b,
    const float* __restrict__ h1f, const float* __restrict__ h1b,
    const float* __restrict__ w2f, const float* __restrict__ w2b,
    const float* __restrict__ h2f, const float* __restrict__ h2b,
    const float* __restrict__ wa1, const float* __restrict__ wa2,
    uint32_t* __restrict__ wpk)
{
    int i = blockIdx.x * 256 + threadIdx.x;
    if (i >= WPK_TOTAL) return;
    float v0, v1;
    if (i < 73728) {
        const float *sa, *sb; int K, NKT, base;
        if (i < 8192)       { base = 0;     NKT = 1; K = 21;  sa = w1f; sb = w1b; }
        else if (i < 24576) { base = 8192;  NKT = 2; K = 64;  sa = h1f; sb = h1b; }
        else if (i < 57344) { base = 24576; NKT = 4; K = 128; sa = w2f; sb = w2b; }
        else                { base = 57344; NKT = 2; K = 64;  sa = h2f; sb = h2b; }
        int local = i - base;
        int dsz = 16 * NKT * 256;
        const float* src = sa;
        if (local >= dsz) { src = sb; local -= dsz; }
        int entry = local >> 8;            // (tau*NKT + kt32)
        int lane  = (local & 255) >> 2;
        int j     = local & 3;             // u32 within 4-u32 frag
        int tau = entry / NKT, kt = entry - tau * NKT;
        int row = 16 * tau + (lane & 15);
        int m   = lane >> 4;
        int kb  = kt * 32 + ((j < 2) ? 0 : 16) + 4 * m + 2 * (j & 1);
        v0 = (kb     < K) ? src[row * K + kb]     : 0.f;
        v1 = (kb + 1 < K) ? src[row * K + kb + 1] : 0.f;
    } else {
        int local = i - 73728;
        const float* src = wa1;
        if (local >= 8192) { src = wa2; local -= 8192; }
        int row = local >> 6, p = local & 63;
        int d0 = 2 * p;
        v0 = src[row * 128 + d0];
        v1 = src[row * 128 + d0 + 1];
    }
    union { _Float16 h[2]; uint32_t u; } x;
    x.h[0] = (_Float16)v0; x.h[1] = (_Float16)v1;
    wpk[i] = x.u;
}

// ---------------------------------------------------------------------------
// Kernel 1: graph stage — frozen (round-10 version).
// ---------------------------------------------------------------------------
struct GWk {
    float    nf[10][10];
    uint32_t xhp[10][64];
    uint32_t hp[10][64];
    float    as_[10][4], ad_[10][4];
    float    al[30][4];
    float    xh2[10][10];
    float    as2[10], ad2[10], al2[30];
    float    mp[10][10];
    float    agg[10][10];
    float    g[10][33];
    float    gagg[10][33];
    float    bf[10][10];
};

__global__ __launch_bounds__(512) void graph_kernel(
    const float* __restrict__ M,
    const float* __restrict__ W1, const float* __restrict__ as1,
    const float* __restrict__ ad1, const float* __restrict__ b1,
    const float* __restrict__ W2, const float* __restrict__ as2,
    const float* __restrict__ ad2, const float* __restrict__ b2,
    const float* __restrict__ gWrel1, const float* __restrict__ gWroot1,
    const float* __restrict__ gb1,
    const float* __restrict__ gWrel2, const float* __restrict__ gWroot2,
    const float* __restrict__ gb2,
    float* __restrict__ xseq)
{
    __shared__ __align__(16) GWk gw[4];
    __shared__ __align__(16) uint32_t sw2p[640];
    __shared__ uint32_t sa1p[64], sd1p[64];
    __shared__ float swrel1[320], swroot1[320];
    __shared__ float swrel2[320], swroot2[320];
    __shared__ __align__(16) float sb1[128];
    __shared__ float sb2[12], sgb1[32], sgb2[12];
    __shared__ int sin_start[12], sin_edge[32];
    __shared__ int sgin_start[12], sgin_src[20], ssrc[20], sdst[20];

    const int tid = threadIdx.x;
    const int wid = tid >> 6;
    const int k   = wid >> 1;
    const int role= wid & 1;
    const int l   = tid & 63;
    const int b   = blockIdx.x * 4 + k;

    for (int i = tid; i < 640; i += 512) {
        int c = i >> 6, j = i & 63;
        sw2p[i] = pk2(W2[(2 * j) * 10 + c], W2[(2 * j + 1) * 10 + c]);
    }
    if (tid < 64)       sa1p[tid]      = pk2(as1[2 * tid], as1[2 * tid + 1]);
    else if (tid < 128) sd1p[tid - 64] = pk2(ad1[2 * (tid - 64)], ad1[2 * (tid - 64) + 1]);
    for (int i = tid; i < 320; i += 512) {
        swrel1[i] = gWrel1[i]; swroot1[i] = gWroot1[i];
        swrel2[i] = gWrel2[i]; swroot2[i] = gWroot2[i];
    }
    if (tid < 128) sb1[tid] = b1[tid];
    if (tid >= 128 && tid < 138) sb2[tid - 128] = b2[tid - 128];
    if (tid >= 144 && tid < 176) sgb1[tid - 144] = gb1[tid - 144];
    if (tid >= 176 && tid < 186) sgb2[tid - 176] = gb2[tid - 176];
    if (tid >= 192 && tid < 203) {
        sin_start[tid - 192]  = c_in_start[tid - 192];
        sgin_start[tid - 192] = c_gin_start[tid - 192];
    }
    if (tid >= 203 && tid < 233) sin_edge[tid - 203] = c_in_edge[tid - 203];
    if (tid >= 233 && tid < 253) {
        int e = tid - 233;
        sgin_src[e] = c_gin_src[e]; ssrc[e] = c_src[e]; sdst[e] = c_dst[e];
    }

    GWk& Wv = gw[k];
    float2 w1r[10];
    if (role == 0) {
        const float* Mb = M + (size_t)b * 70;
        for (int i = l; i < 100; i += 64) {
            int n = i / 10, f = i - n * 10;
            Wv.nf[n][f] = (n < 7) ? Mb[n * 10 + f] : 0.f;
        }
        #pragma unroll
        for (int f = 0; f < 10; f++)
            w1r[f] = *(const float2*)(W1 + f * 128 + 2 * l);
    }
    __syncthreads();

    if (role == 0) {
        #pragma unroll
        for (int n = 0; n < 10; n++) {
            float a0 = 0.f, a1 = 0.f;
            #pragma unroll
            for (int f = 0; f < 10; f++) {
                float x = Wv.nf[n][f];
                a0 += x * w1r[f].x; a1 += x * w1r[f].y;
            }
            Wv.xhp[n][l] = pk2(a0, a1);
        }
        SBAR();

        if (l < 40) {
            int n = l >> 2, h = l & 3;
            float va = 0.f, vd = 0.f;
            #pragma unroll
            for (int cp = 0; cp < 16; cp++) {
                uint32_t x = Wv.xhp[n][h * 16 + cp];
                va = d2(x, sa1p[h * 16 + cp], va);
                vd = d2(x, sd1p[h * 16 + cp], vd);
            }
            Wv.as_[n][h] = va; Wv.ad_[n][h] = vd;
        }
        SBAR();

        for (int i = l; i < 120; i += 64) {
            int e = i >> 2, h = i & 3;
            int sn = (e < 20) ? ssrc[e] : e - 20;
            int dn = (e < 20) ? sdst[e] : e - 20;
            float v = Wv.as_[sn][h] + Wv.ad_[dn][h];
            Wv.al[e][h] = (v >= 0.f) ? v : 0.2f * v;
        }
        SBAR();

        if (l < 40) {
            int n = l >> 2, h = l & 3;
            int st = sin_start[n], en = sin_start[n + 1];
            float m = -1e30f;
            for (int j = st; j < en; j++) m = fmaxf(m, Wv.al[sin_edge[j]][h]);
            float den = 0.f;
            for (int j = st; j < en; j++) den += __expf(Wv.al[sin_edge[j]][h] - m);
            float inv = 1.f / den;
            for (int j = st; j < en; j++) {
                int e = sin_edge[j];
                Wv.al[e][h] = __expf(Wv.al[e][h] - m) * inv;
            }
        }
        SBAR();

        for (int i = l; i < 640; i += 64) {
            int n = i >> 6, p = i & 63;
            int h = p >> 4;
            int st = sin_start[n], en = sin_start[n + 1];
            float o0 = sb1[2 * p], o1 = sb1[2 * p + 1];
            for (int j = st; j < en; j++) {
                int e = sin_edge[j];
                int sn = (e < 20) ? ssrc[e] : e - 20;
                float al = Wv.al[e][h];
                float2 xf = upk2(Wv.xhp[sn][p]);
                o0 += al * xf.x; o1 += al * xf.y;
            }
            Wv.hp[n][p] = pk2(fmaxf(o0, 0.f), fmaxf(o1, 0.f));
        }
        SBAR();

        for (int i = l; i < 100; i += 64) {
            int n = i / 10, c = i - (i / 10) * 10;
            float a0 = 0.f, a1 = 0.f;
            #pragma unroll 8
            for (int j = 0; j < 64; j += 2) {
                a0 = d2(Wv.hp[n][j],     sw2p[c * 64 + j],     a0);
                a1 = d2(Wv.hp[n][j + 1], sw2p[c * 64 + j + 1], a1);
            }
            Wv.xh2[n][c] = a0 + a1;
        }
        SBAR();

        if (l < 20) {
            int n = (l < 10) ? l : l - 10;
            const float* av = (l < 10) ? as2 : ad2;
            float v = 0.f;
            #pragma unroll
            for (int c = 0; c < 10; c++) v += Wv.xh2[n][c] * av[c];
            if (l < 10) Wv.as2[n] = v; else Wv.ad2[n] = v;
        }
        SBAR();
        if (l < 30) {
            int e = l;
            int sn = (e < 20) ? ssrc[e] : e - 20;
            int dn = (e < 20) ? sdst[e] : e - 20;
            float v = Wv.as2[sn] + Wv.ad2[dn];
            Wv.al2[e] = (v >= 0.f) ? v : 0.2f * v;
        }
        SBAR();
        if (l < 10) {
            int st = sin_start[l], en = sin_start[l + 1];
            float m = -1e30f;
            for (int j = st; j < en; j++) m = fmaxf(m, Wv.al2[sin_edge[j]]);
            float den = 0.f;
            for (int j = st; j < en; j++) den += __expf(Wv.al2[sin_edge[j]] - m);
            float inv = 1.f / den;
            for (int j = st; j < en; j++) Wv.al2[sin_edge[j]] = __expf(Wv.al2[sin_edge[j]] - m) * inv;
        }
        SBAR();
        for (int i = l; i < 100; i += 64) {
            int n = i / 10, c = i - (i / 10) * 10;
            int st = sin_start[n], en = sin_start[n + 1];
            float o = sb2[c];
            for (int j = st; j < en; j++) {
                int e = sin_edge[j];
                int sn = (e < 20) ? ssrc[e] : e - 20;
                o += Wv.al2[e] * Wv.xh2[sn][c];
            }
            Wv.mp[n][c] = o;
        }
    } else {
        for (int i = l; i < 100; i += 64) {
            int n = i / 10, f = i - (i / 10) * 10;
            int st = sgin_start[n], en = sgin_start[n + 1];
            float a = 0.f;
            for (int j = st; j < en; j++) a += Wv.nf[sgin_src[j]][f];
            Wv.agg[n][f] = a;
        }
        SBAR();
        for (int i = l; i < 320; i += 64) {
            int n = i >> 5, c = i & 31;
            float v = sgb1[c];
            #pragma unroll
            for (int f = 0; f < 10; f++)
                v += Wv.agg[n][f] * swrel1[f * 32 + c] + Wv.nf[n][f] * swroot1[f * 32 + c];
            Wv.g[n][c] = fmaxf(v, 0.f);
        }
        SBAR();
        for (int i = l; i < 320; i += 64) {
            int n = i >> 5, c = i & 31;
            int st = sgin_start[n], en = sgin_start[n + 1];
            float a = 0.f;
            for (int j = st; j < en; j++) a += Wv.g[sgin_src[j]][c];
            Wv.gagg[n][c] = a;
        }
        SBAR();
        for (int i = l; i < 100; i += 64) {
            int n = i / 10, c = i - (i / 10) * 10;
            float v = sgb2[c];
            #pragma unroll
            for (int f = 0; f < 32; f++)
                v += Wv.gagg[n][f] * swrel2[f * 10 + c] + Wv.g[n][f] * swroot2[f * 10 + c];
            Wv.bf[n][c] = v;
        }
    }
    __syncthreads();

    if (role == 1) {
        float* xo = xseq + (size_t)b * 210;
        for (int i = l; i < 210; i += 64) {
            int t = i / 21, kk = i - (i / 21) * 21;
            float v;
            if (kk < 7)       v = Wv.nf[kk][t];
            else if (kk < 14) v = Wv.mp[kk - 7][t];
            else              v = Wv.bf[kk - 14][t];
            xo[i] = v;
        }
    }
}

// ---------------------------------------------------------------------------
// seq LDS regions (per block = 8 samples):
//   sR1 [8][680]u32 : X2 f16 [8][10][36] -> attn Q f16 [s][10][136] -> A2
//   sO2 [8][680]u32 : BiLSTM output f16 [s][10][136]
//   sSC [8][104]f32 : attn scores
//   sH  [2dir][2buf][8][72]f16 : hidden state (double-buffered)
// ---------------------------------------------------------------------------

// One BiLSTM layer, both directions concurrently. 4 waves, K=32 MFMA.
// C/D: col = l&15 (gate within tile), row = 4*(l>>4)+reg (sample) [16x16].
// A: row = l&15 (&7 for 8 samples), chunk0 k=4*(l>>4)+e, chunk1 k=16+...
template<int L>
__device__ __forceinline__ void rec_layer(
    const uint32_t* __restrict__ wpk,
    const float* __restrict__ bf, const float* __restrict__ bb,
    uint32_t* __restrict__ sR1, uint32_t* __restrict__ sO2,
    uint32_t* __restrict__ sH, int w, int l)
{
    constexpr int NKT = (L == 1) ? 1 : 4;   // xw kt32 count
    const uint32_t* bih = wpk + ((L == 1) ? IH1O : IH2O);
    const uint32_t* bhh = wpk + ((L == 1) ? HH1O : HH2O);
    const int dir = w >> 1;
    const int ub  = (w & 1) * 2;
    bih += dir * 16 * NKT * 256;
    bhh += dir * 16 * 2 * 256;
    const float* bias = dir ? bb : bf;
    const int ln = l & 15, lg = l >> 4;
    const int arow = l & 7, asub = 4 * lg;
    float bv[2][4];
    #pragma unroll
    for (int up = 0; up < 2; ++up)
        #pragma unroll
        for (int g = 0; g < 4; ++g)
            bv[up][g] = bias[64 * g + 16 * (ub + up) + ln];
    float cs[2][4] = {{0.f,0.f,0.f,0.f},{0.f,0.f,0.f,0.f}};
    const _Float16* Axh = (const _Float16*)sR1;
    _Float16* Hh  = (_Float16*)sH;
    _Float16* O2h = (_Float16*)sO2;
    for (int ss = 0; ss < 10; ++ss) {
        const int t = dir ? 9 - ss : ss;
        const int cur = ss & 1;
        f16x8 ax[NKT];
        #pragma unroll
        for (int kt = 0; kt < NKT; ++kt) {
            const int fo = (L == 1) ? (arow * 360 + t * 36 + kt * 32 + asub)
                                    : (arow * 1360 + t * 136 + kt * 32 + asub);
            ax[kt] = ldfragA(Axh + fo);
        }
        f16x8 ah[2];
        #pragma unroll
        for (int kt = 0; kt < 2; ++kt)
            ah[kt] = ldfragA(Hh + ((dir * 2 + cur) * 8 + arow) * 72 + kt * 32 + asub);
        #pragma unroll
        for (int up = 0; up < 2; ++up) {
            const int v = ub + up;
            f32x4 G[4];
            #pragma unroll
            for (int g = 0; g < 4; ++g) {
                const int tau = 4 * g + v;
                f32x4 c = { bv[up][g], bv[up][g], bv[up][g], bv[up][g] };
                #pragma unroll
                for (int kt = 0; kt < NKT; ++kt)
                    c = mfma32(ax[kt], ldfragB(bih + (tau * NKT + kt) * 256 + 4 * l), c);
                #pragma unroll
                for (int kt = 0; kt < 2; ++kt)
                    c = mfma32(ah[kt], ldfragB(bhh + (tau * 2 + kt) * 256 + 4 * l), c);
                G[g] = c;
            }
            if (l < 32) {   // rows 0..7 = real samples
                #pragma unroll
                for (int r = 0; r < 4; ++r) {
                    const int s = asub + r;
                    const float ig = fsig(G[0][r]), fg = fsig(G[1][r]);
                    const float gg = ftanh(G[2][r]), og = fsig(G[3][r]);
                    const float c2 = fg * cs[up][r] + ig * gg;
                    cs[up][r] = c2;
                    const float hv = og * ftanh(c2);
                    const int u = 16 * v + ln;
                    Hh[((dir * 2 + (1 - cur)) * 8 + s) * 72 + u] = (_Float16)hv;
                    O2h[s * 1360 + t * 136 + dir * 64 + u] = (_Float16)hv;
                }
            }
        }
        __syncthreads();
    }
}

// Self-attention for ONE sample, one full wave (frozen round-7 code).
__device__ __forceinline__ void attn_one(
    const uint32_t* __restrict__ wa, const float* __restrict__ ba,
    uint32_t* __restrict__ sR1, const uint32_t* __restrict__ sO2,
    float* __restrict__ sSC, int l, int s, float* __restrict__ outg)
{
    const uint32_t* O2s = sO2 + s * 680;
    uint32_t* Q2s = sR1 + s * 680;
    float* sc = sSC + s * 104;

    float qa0[10], qa1[10];
    {
        float b0 = ba[l], b1 = ba[64 + l];
        #pragma unroll
        for (int t = 0; t < 10; t++) { qa0[t] = b0; qa1[t] = b1; }
    }
    #pragma unroll 4
    for (int c = 0; c < 16; c++) {
        uint4 w0 = *(const uint4*)(wa + l * 64 + c * 4);
        uint4 w1 = *(const uint4*)(wa + (64 + l) * 64 + c * 4);
        #pragma unroll
        for (int t = 0; t < 10; t++) {
            uint4 o = *(const uint4*)(O2s + t * 68 + c * 4);
            qa0[t] = d2(w0.w, o.w, d2(w0.z, o.z, d2(w0.y, o.y, d2(w0.x, o.x, qa0[t]))));
            qa1[t] = d2(w1.w, o.w, d2(w1.z, o.z, d2(w1.y, o.y, d2(w1.x, o.x, qa1[t]))));
        }
    }
    _Float16* q2h = (_Float16*)Q2s;
    #pragma unroll
    for (int t = 0; t < 10; t++) {
        q2h[t * 136 + l]      = (_Float16)ftanh(qa0[t]);
        q2h[t * 136 + 64 + l] = (_Float16)ftanh(qa1[t]);
    }
    #pragma unroll
    for (int r = 0; r < 2; r++) {
        int idx = l + r * 64;
        if (idx < 100) {
            int q = idx / 10, k = idx - 10 * q;
            float sv = 0.f;
            #pragma unroll
            for (int m = 0; m < 16; m++) {
                uint4 a = *(const uint4*)(Q2s + q * 68 + m * 4);
                uint4 b = *(const uint4*)(O2s + k * 68 + m * 4);
                sv = d2(a.w, b.w, d2(a.z, b.z, d2(a.y, b.y, d2(a.x, b.x, sv))));
            }
            sc[idx] = sv;
        }
    }
    if (l < 10) {
        float m = -1e30f;
        #pragma unroll
        for (int k = 0; k < 10; k++) m = fmaxf(m, sc[l * 10 + k]);
        float den = 0.f, e[10];
        #pragma unroll
        for (int k = 0; k < 10; k++) { e[k] = __expf(sc[l * 10 + k] - m); den += e[k]; }
        float inv = 1.f / den;
        #pragma unroll
        for (int k = 0; k < 10; k++) sc[l * 10 + k] = e[k] * inv;
    }
    float of0[10], of1[10];
    {
        const _Float16* o2h = (const _Float16*)O2s;
        #pragma unroll
        for (int k = 0; k < 10; k++) {
            of0[k] = (float)o2h[k * 136 + l];
            of1[k] = (float)o2h[k * 136 + 64 + l];
        }
    }
    float pa0[10], pa1[10];
    #pragma unroll
    for (int t = 0; t < 10; t++) { pa0[t] = 0.f; pa1[t] = 0.f; }
    #pragma unroll
    for (int k = 0; k < 10; k++) {
        float o0 = of0[k], o1 = of1[k];
        #pragma unroll
        for (int t = 0; t < 10; t++) {
            float sv = sc[t * 10 + k];
            pa0[t] += sv * o0; pa1[t] += sv * o1;
        }
    }
    if (outg) {
        float s0 = 0.f, s1 = 0.f;
        #pragma unroll
        for (int t = 0; t < 10; t++) { s0 += pa0[t]; s1 += pa1[t]; }
        outg[l] = s0 * 0.1f; outg[64 + l] = s1 * 0.1f;
    } else {
        _Float16* a2h = (_Float16*)Q2s;   // A2 overwrites Q (Q dead after scores)
        #pragma unroll
        for (int t = 0; t < 10; t++) {
            a2h[t * 136 + l]      = (_Float16)pa0[t];
            a2h[t * 136 + 64 + l] = (_Float16)pa1[t];
        }
    }
}

// ---------------------------------------------------------------------------
// Kernel 2: sequence stage — 8 samples per block, 4 waves, K=32 MFMA rec.
// ---------------------------------------------------------------------------
__global__ __launch_bounds__(256) void seq_kernel(
    const float* __restrict__ xseq, const uint32_t* __restrict__ wpk,
    const float* __restrict__ b1f, const float* __restrict__ b1b,
    const float* __restrict__ b2f, const float* __restrict__ b2b,
    const float* __restrict__ ba1, const float* __restrict__ ba2,
    float* __restrict__ xbar)
{
    __shared__ __align__(16) uint32_t sR1[8 * 680];
    __shared__ __align__(16) uint32_t sO2[8 * 680];
    __shared__ __align__(16) float    sSC[8 * 104];
    __shared__ __align__(16) uint32_t sH[1152];
    const int tid = threadIdx.x;
    const int w = tid >> 6, l = tid & 63;
    const int b0 = blockIdx.x * 8;

    // stage X: xseq f32 [8][10][21] -> f16 [8][10][36] (zero-padded)
    {
        _Float16* xh = (_Float16*)sR1;
        const float* xs = xseq + (size_t)b0 * 210;
        for (int i = tid; i < 2880; i += 256) {
            int s = i / 360, r = i - s * 360;
            int t = r / 36, k = r - t * 36;
            float v = (k < 21) ? xs[s * 210 + t * 21 + k] : 0.f;
            xh[s * 360 + t * 36 + k] = (_Float16)v;
        }
    }
    for (int i = tid; i < 1152; i += 256) sH[i] = 0;
    __syncthreads();

    rec_layer<1>(wpk, b1f, b1b, sR1, sO2, sH, w, l);

    for (int smp = 0; smp < 2; ++smp)
        attn_one(wpk + WA1O, ba1, sR1, sO2, sSC, l, 2 * w + smp, nullptr);
    __syncthreads();
    for (int i = tid; i < 1152; i += 256) sH[i] = 0;
    __syncthreads();

    rec_layer<2>(wpk, b2f, b2b, sR1, sO2, sH, w, l);

    for (int smp = 0; smp < 2; ++smp) {
        int s = 2 * w + smp;
        attn_one(wpk + WA2O, ba2, sR1, sO2, sSC, l, s,
                 xbar + (size_t)(b0 + s) * 128);
    }
}

// ---------------------------------------------------------------------------
// Kernel 3: FC  out[b][u] = xbar[b] . W[u] + bias[u]
// ---------------------------------------------------------------------------
__global__ __launch_bounds__(256) void fc_kernel(
    const float* __restrict__ xbar, const float* __restrict__ W,
    const float* __restrict__ fb, float* __restrict__ out, int B)
{
    __shared__ __align__(16) float s_xb[64 * 132];
    const int tid = threadIdx.x;
    const int b0 = blockIdx.y * 64;
    const int u0 = blockIdx.x * 64;

    for (int i = tid; i < 64 * 128; i += 256) {
        int s = i >> 7, k = i & 127;
        int bb = b0 + s;
        s_xb[s * 132 + k] = (bb < B) ? xbar[(size_t)bb * 128 + k] : 0.f;
    }
    __syncthreads();

    const int tx = tid & 15, ty = tid >> 4;
    float acc[4][4] = {};
    for (int k = 0; k < 128; k += 4) {
        float4 wv[4], xv[4];
        #pragma unroll
        for (int j = 0; j < 4; j++) {
            int u = u0 + tx + 16 * j;
            int uc = (u < 1000) ? u : 999;
            wv[j] = *(const float4*)(W + (size_t)uc * 128 + k);
        }
        #pragma unroll
        for (int si = 0; si < 4; si++) {
            int s = ty + 16 * si;
            xv[si] = *(const float4*)(s_xb + s * 132 + k);
        }
        #pragma unroll
        for (int j = 0; j < 4; j++)
            #pragma unroll
            for (int si = 0; si < 4; si++)
                acc[j][si] += wv[j].x*xv[si].x + wv[j].y*xv[si].y
                            + wv[j].z*xv[si].z + wv[j].w*xv[si].w;
    }
    #pragma unroll
    for (int j = 0; j < 4; j++) {
        int u = u0 + tx + 16 * j;
        if (u < 1000) {
            float bb = fb[u];
            #pragma unroll
            for (int si = 0; si < 4; si++) {
                int bsm = b0 + ty + 16 * si;
                if (bsm < B) out[(size_t)bsm * 1000 + u] = acc[j][si] + bb;
            }
        }
    }
}

// ---------------------------------------------------------------------------
extern "C" void kernel_launch(void* const* d_in, const int* in_sizes, int n_in,
                              void* d_out, int out_size, void* d_ws, size_t ws_size,
                              hipStream_t stream)
{
    const float* M       = (const float*)d_in[0];
    const float* ga1_W   = (const float*)d_in[1];
    const float* ga1_as  = (const float*)d_in[2];
    const float* ga1_ad  = (const float*)d_in[3];
    const float* ga1_b   = (const float*)d_in[4];
    const float* ga2_W   = (const float*)d_in[5];
    const float* ga2_as  = (const float*)d_in[6];
    const float* ga2_ad  = (const float*)d_in[7];
    const float* ga2_b   = (const float*)d_in[8];
    const float* gp1_Wrel  = (const float*)d_in[9];
    const float* gp1_Wroot = (const float*)d_in[10];
    const float* gp1_b     = (const float*)d_in[11];
    const float* gp2_Wrel  = (const float*)d_in[12];
    const float* gp2_Wroot = (const float*)d_in[13];
    const float* gp2_b     = (const float*)d_in[14];
    const float* l1f_Wih = (const float*)d_in[15];
    const float* l1f_Whh = (const float*)d_in[16];
    const float* l1f_b   = (const float*)d_in[17];
    const float* l1b_Wih = (const float*)d_in[18];
    const float* l1b_Whh = (const float*)d_in[19];
    const float* l1b_b   = (const float*)d_in[20];
    const float* l2f_Wih = (const float*)d_in[21];
    const float* l2f_Whh = (const float*)d_in[22];
    const float* l2f_b   = (const float*)d_in[23];
    const float* l2b_Wih = (const float*)d_in[24];
    const float* l2b_Whh = (const float*)d_in[25];
    const float* l2b_b   = (const float*)d_in[26];
    const float* a1_Wa   = (const float*)d_in[27];
    const float* a1_ba   = (const float*)d_in[28];
    const float* a2_Wa   = (const float*)d_in[29];
    const float* a2_ba   = (const float*)d_in[30];
    const float* fc_W    = (const float*)d_in[31];
    const float* fc_b    = (const float*)d_in[32];

    const int B = in_sizes[0] / 70;    // 32768

    float* xseq = (float*)d_ws;                                       // [B,10,21]
    float* xbar = (float*)((char*)d_ws + (size_t)B * 210 * 4);        // [B,128]
    uint32_t* wpk = (uint32_t*)((char*)d_ws + (size_t)B * 210 * 4
                                            + (size_t)B * 128 * 4);   // packed weights

    prep_kernel<<<(WPK_TOTAL + 255) / 256, 256, 0, stream>>>(
        l1f_Wih, l1b_Wih, l1f_Whh, l1b_Whh,
        l2f_Wih, l2b_Wih, l2f_Whh, l2b_Whh,
        a1_Wa, a2_Wa, wpk);

    graph_kernel<<<B / 4, 512, 0, stream>>>(M,
        ga1_W, ga1_as, ga1_ad, ga1_b,
        ga2_W, ga2_as, ga2_ad, ga2_b,
        gp1_Wrel, gp1_Wroot, gp1_b,
        gp2_Wrel, gp2_Wroot, gp2_b,
        xseq);

    seq_kernel<<<B / 8, 256, 0, stream>>>(xseq, wpk,
        l1f_b, l1b_b, l2f_b, l2b_b, a1_ba, a2_ba, xbar);

    dim3 fgrid((1000 + 63) / 64, (B + 63) / 64);
    fc_kernel<<<fgrid, 256, 0, stream>>>(xbar, fc_W, fc_b, (float*)d_out, B);
}